// Round 11
// baseline (226.985 us; speedup 1.0000x reference)
//
#include <hip/hip_runtime.h>

// Fused MHA: qkv = x@Wqkv+b; attn per head; out = vals@Wout+b
// B=4, S=2048, D=1024, H=16, Hd=64. Internal compute bf16 MFMA + fp32 accum.
// Round 11: GEMM1 = 256x128 tile counted-vmcnt pipeline (r10 template, BN
// halved) -> grid 768 = exactly 3 waves of 256 CUs, zero tail. LDS 96KB.
// GEMM2 / attn unchanged (r8). static guard removed (harness rule).

typedef short bf16x8 __attribute__((ext_vector_type(8)));
typedef short bf16x4 __attribute__((ext_vector_type(4)));
typedef float f32x4 __attribute__((ext_vector_type(4)));
typedef float f32x16 __attribute__((ext_vector_type(16)));
typedef unsigned u32x4 __attribute__((ext_vector_type(4)));

#define DIMM 1024
#define NH 16
#define HD 64
#define SEQ 2048
#define NB 4
#define MTOT (NB * SEQ)  // 8192
#define SCQ 0.18033688f  // 0.125 * log2(e), folded into Q

__device__ __forceinline__ short f2bf(float f) {
  __bf16 h = (__bf16)f;
  return __builtin_bit_cast(short, h);
}

__device__ __forceinline__ unsigned cvtpk(float lo, float hi) {
  unsigned d;
  asm("v_cvt_pk_bf16_f32 %0, %1, %2" : "=v"(d) : "v"(lo), "v"(hi));
  return d;
}

__device__ __forceinline__ void gload16(const short* g, const short* l) {
  __builtin_amdgcn_global_load_lds(
      (const __attribute__((address_space(1))) unsigned int*)g,
      (__attribute__((address_space(3))) unsigned int*)l, 16, 0, 0);
}

// ---------------- x fp32 -> bf16 ----------------
__global__ __launch_bounds__(256) void k_cvt(const float* __restrict__ in,
                                             short* __restrict__ out, int n8) {
  const int stride = gridDim.x * blockDim.x;
  for (int i = blockIdx.x * blockDim.x + threadIdx.x; i < n8; i += stride) {
    const float4* p = (const float4*)(in + (size_t)i * 8);
    float4 a = p[0], b = p[1];
    bf16x8 h;
    h[0] = f2bf(a.x); h[1] = f2bf(a.y); h[2] = f2bf(a.z); h[3] = f2bf(a.w);
    h[4] = f2bf(b.x); h[5] = f2bf(b.y); h[6] = f2bf(b.z); h[7] = f2bf(b.w);
    *(bf16x8*)(out + (size_t)i * 8) = h;
  }
}

// ---------------- transpose + fp32->bf16: out[n][k] = in[k][n] ----------------
__global__ void k_transpose(const float* __restrict__ in, short* __restrict__ out,
                            int K, int N) {
  __shared__ float tile[32][33];
  const int n0 = blockIdx.x * 32, k0 = blockIdx.y * 32;
  const int tx = threadIdx.x, ty = threadIdx.y;
#pragma unroll
  for (int i = 0; i < 32; i += 8)
    tile[ty + i][tx] = in[(size_t)(k0 + ty + i) * N + n0 + tx];
  __syncthreads();
#pragma unroll
  for (int i = 0; i < 32; i += 8)
    out[(size_t)(n0 + ty + i) * K + k0 + tx] = f2bf(tile[tx][ty + i]);
}

// ---------------- GEMM1: 256x128 tile, counted-vmcnt pipeline ----------------
// LDS image (A [256][64], B [128][64]): [r][slot] holds global slot^(r&7);
// DMA dest linear, source pre-swizzled. Per K-tile t:
//   h1{issue B(t+1) [2]; MFMA i0-3} vmcnt(2);bar   (drains prior A-high)
//   h2{issue A(t+1) [4, low-first]; MFMA i4-7} vmcnt(2);bar  (A-high rides on)
__global__ __launch_bounds__(512, 1) void k_gemm_qkv(
    const short* __restrict__ A, const short* __restrict__ Bt,
    const float* __restrict__ bias,
    short* __restrict__ qw, short* __restrict__ kw, short* __restrict__ vtg) {
  extern __shared__ short smem[];
  short* const Ab0 = smem;             // [256][64]
  short* const Ab1 = smem + 16384;
  short* const Bb0 = smem + 32768;     // [128][64]
  short* const Bb1 = smem + 40960;
  const int tid = threadIdx.x, lane = tid & 63, w = tid >> 6;
  const int wm = w >> 2, wn = w & 3;
  const int fr = lane & 15, fg = lane >> 4;
  const int fsw = fr & 7;

  // XCD-chunked remap: 768 blocks (768%8==0), 96/XCD; bm fastest -> B L2 reuse
  const int flat = blockIdx.x;
  const int wrk = (flat & 7) * 96 + (flat >> 3);
  const int bm = wrk & 31, bn = wrk >> 5;

  const short* Ap = A + (size_t)bm * 256 * DIMM;
  const short* Bp = Bt + (size_t)bn * 128 * DIMM;
  // per-lane staged-source offset: row lane>>3, slot (lane&7)^(lane>>3)
  const int soff = (lane >> 3) * DIMM + (((lane & 7) ^ (lane >> 3)) << 3);

  f32x4 acc[8][2] = {};

  // B: 16 chunks of 8 rows -> 2/wave. A: 32 chunks -> 4/wave, low chunks
  // (rows 0-63,128-191; feed i0-3 of both wm) first, high chunks last.
#define STB(dst, k0)                                                               \
  {                                                                                \
    gload16(Bp + (size_t)(w)*8 * DIMM + soff + (k0), (dst) + w * 512);             \
    gload16(Bp + (size_t)(8 + w) * 8 * DIMM + soff + (k0), (dst) + (8 + w) * 512); \
  }
#define STA(dst, k0)                                                                 \
  {                                                                                  \
    gload16(Ap + (size_t)(w)*8 * DIMM + soff + (k0), (dst) + w * 512);               \
    gload16(Ap + (size_t)(16 + w) * 8 * DIMM + soff + (k0), (dst) + (16 + w) * 512); \
    gload16(Ap + (size_t)(8 + w) * 8 * DIMM + soff + (k0), (dst) + (8 + w) * 512);   \
    gload16(Ap + (size_t)(24 + w) * 8 * DIMM + soff + (k0), (dst) + (24 + w) * 512); \
  }

  STB(Bb0, 0);
  STA(Ab0, 0);
  asm volatile("s_waitcnt vmcnt(0)\n\ts_barrier" ::: "memory");

  for (int t = 0; t < 16; ++t) {
    const short* Ac = (t & 1) ? Ab1 : Ab0;
    const short* Bc = (t & 1) ? Bb1 : Bb0;
    short* An = (t & 1) ? Ab0 : Ab1;
    short* Bn = (t & 1) ? Bb0 : Bb1;
    if (t < 15) STB(Bn, (t + 1) * 64);

    bf16x8 bF[2][2];
#pragma unroll
    for (int j = 0; j < 2; j++)
#pragma unroll
      for (int ks = 0; ks < 2; ks++)
        bF[j][ks] = *(const bf16x8*)&Bc[(wn * 32 + j * 16 + fr) * 64 +
                                        (((ks * 4 + fg) ^ fsw) << 3)];
    __builtin_amdgcn_s_setprio(1);
#pragma unroll
    for (int i = 0; i < 4; i++) {
      const int R = (wm * 128 + i * 16 + fr) * 64;
#pragma unroll
      for (int ks = 0; ks < 2; ks++) {
        const bf16x8 aF = *(const bf16x8*)&Ac[R + (((ks * 4 + fg) ^ fsw) << 3)];
#pragma unroll
        for (int j = 0; j < 2; j++)
          acc[i][j] = __builtin_amdgcn_mfma_f32_16x16x32_bf16(aF, bF[j][ks], acc[i][j], 0, 0, 0);
      }
    }
    __builtin_amdgcn_s_setprio(0);
    // drain prior tile's A-high (leaves B(t+1) in flight); last tile: drain all
    if (t < 15) {
      asm volatile("s_waitcnt vmcnt(2)\n\ts_barrier" ::: "memory");
    } else {
      asm volatile("s_waitcnt vmcnt(0)\n\ts_barrier" ::: "memory");
    }
    if (t < 15) STA(An, (t + 1) * 64);
    __builtin_amdgcn_s_setprio(1);
#pragma unroll
    for (int i = 4; i < 8; i++) {
      const int R = (wm * 128 + i * 16 + fr) * 64;
#pragma unroll
      for (int ks = 0; ks < 2; ks++) {
        const bf16x8 aF = *(const bf16x8*)&Ac[R + (((ks * 4 + fg) ^ fsw) << 3)];
#pragma unroll
        for (int j = 0; j < 2; j++)
          acc[i][j] = __builtin_amdgcn_mfma_f32_16x16x32_bf16(aF, bF[j][ks], acc[i][j], 0, 0, 0);
      }
    }
    __builtin_amdgcn_s_setprio(0);
    if (t < 15) {
      // next h1 needs B(t+1)[2 oldest] + A-low(t+1)[next 2]; A-high may pend
      asm volatile("s_waitcnt vmcnt(2)\n\ts_barrier" ::: "memory");
    }
  }
#undef STB
#undef STA

#pragma unroll
  for (int i = 0; i < 8; i++) {
    const int row0 = bm * 256 + wm * 128 + i * 16 + fg * 4;
    const int bb = row0 >> 11, s0 = row0 & 2047;
#pragma unroll
    for (int j = 0; j < 2; j++) {
      const int col = bn * 128 + wn * 32 + j * 16 + fr;
      const int h = col / 192;
      const int rem = col - h * 192;
      const int which = rem >> 6, d = rem & 63;
      const float bs = bias[col];
      if (which == 2) {
        bf16x4 pk;
#pragma unroll
        for (int r = 0; r < 4; r++) pk[r] = f2bf(acc[i][j][r] + bs);
        *(bf16x4*)&vtg[((size_t)((bb * NH + h) * HD + d)) * SEQ + s0] = pk;
      } else {
        short* dst = which == 0 ? qw : kw;
        const float scl = which == 0 ? SCQ : 1.f;
#pragma unroll
        for (int r = 0; r < 4; r++)
          dst[((size_t)((bb * NH + h) * SEQ + s0 + r)) * HD + d] =
              f2bf((acc[i][j][r] + bs) * scl);
      }
    }
  }
}

// ---------------- flash attention: 32x32x16 core, LDS-staged K/V (r8) ----------------
__global__ __launch_bounds__(256, 4) void k_attn(
    const short* __restrict__ qw, const short* __restrict__ kw,
    const short* __restrict__ vt, short* __restrict__ vals) {
  __shared__ alignas(16) short Kls[2][64][64];
  __shared__ alignas(16) short Vls[2][64][64];   // [d][key]
  const int tid = threadIdx.x, lane = tid & 63, w = tid >> 6;
  const int l31 = lane & 31, hi = lane >> 5;
  const int swz = (l31 & 7) ^ ((l31 & 8) >> 1);  // read-side row swizzle

  const int flat = blockIdx.x;
  const int wrk = (flat & 7) * 128 + (flat >> 3);
  const int qt = wrk & 15, bh = wrk >> 4;

  const short* Qp = qw + (size_t)bh * SEQ * HD;
  const short* Kp = kw + (size_t)bh * SEQ * HD;
  const short* Vtp = vt + (size_t)bh * HD * SEQ;

  const int q0 = qt * 128 + w * 32;

  bf16x8 qB[4];
#pragma unroll
  for (int dc = 0; dc < 4; dc++)
    qB[dc] = *(const bf16x8*)&Qp[(size_t)(q0 + l31) * HD + dc * 16 + hi * 8];

  bf16x8 onesB;
#pragma unroll
  for (int i = 0; i < 8; i++) onesB[i] = (short)0x3F80;

  f32x16 o0 = {}, o1 = {};
  f32x16 asum = {};

  const int sr8 = lane >> 3;
  const short* kstg = Kp + (size_t)(w * 16 + sr8) * HD;
  const short* vstg = Vtp + (size_t)(w * 16 + sr8) * SEQ;
  const int sslot0 = ((lane & 7) ^ sr8) * 8;
  const int sslot1 = ((lane & 7) ^ sr8 ^ 4) * 8;

  int cur = 0;
  gload16(kstg + sslot0, &Kls[0][w * 16][0]);
  gload16(vstg + sslot0, &Vls[0][w * 16][0]);
  gload16(kstg + (size_t)8 * HD + sslot1, &Kls[0][w * 16 + 8][0]);
  gload16(vstg + (size_t)8 * SEQ + sslot1, &Vls[0][w * 16 + 8][0]);

  for (int t = 0; t < SEQ / 64; t++) {
    __syncthreads();
    if (t + 1 < SEQ / 64) {
      const int kb = (t + 1) * 64;
      gload16(kstg + (size_t)kb * HD + sslot0, &Kls[cur ^ 1][w * 16][0]);
      gload16(vstg + kb + sslot0, &Vls[cur ^ 1][w * 16][0]);
      gload16(kstg + (size_t)(kb + 8) * HD + sslot1, &Kls[cur ^ 1][w * 16 + 8][0]);
      gload16(vstg + (size_t)8 * SEQ + kb + sslot1, &Vls[cur ^ 1][w * 16 + 8][0]);
    }

    f32x16 s0 = {}, s1 = {};
    __builtin_amdgcn_s_setprio(1);
#pragma unroll
    for (int dc = 0; dc < 4; dc++) {
      const bf16x8 k0 =
          *(const bf16x8*)&Kls[cur][l31][((dc * 2 + hi) ^ swz) << 3];
      const bf16x8 k1 =
          *(const bf16x8*)&Kls[cur][32 + l31][((dc * 2 + hi) ^ swz) << 3];
      s0 = __builtin_amdgcn_mfma_f32_32x32x16_bf16(k0, qB[dc], s0, 0, 0, 0);
      s1 = __builtin_amdgcn_mfma_f32_32x32x16_bf16(k1, qB[dc], s1, 0, 0, 0);
    }
    __builtin_amdgcn_s_setprio(0);

#pragma unroll
    for (int r = 0; r < 16; r++) s0[r] = exp2f(s0[r]);
#pragma unroll
    for (int r = 0; r < 16; r++) s1[r] = exp2f(s1[r]);

    u32x4 pf[4];
#pragma unroll
    for (int b2 = 0; b2 < 2; b2++) {
#pragma unroll
      for (int h8 = 0; h8 < 2; h8++) {
        const int rb = h8 * 8;
        unsigned c01, c23, c45, c67;
        if (b2 == 0) {
          c01 = cvtpk(s0[rb + 0], s0[rb + 1]); c23 = cvtpk(s0[rb + 2], s0[rb + 3]);
          c45 = cvtpk(s0[rb + 4], s0[rb + 5]); c67 = cvtpk(s0[rb + 6], s0[rb + 7]);
        } else {
          c01 = cvtpk(s1[rb + 0], s1[rb + 1]); c23 = cvtpk(s1[rb + 2], s1[rb + 3]);
          c45 = cvtpk(s1[rb + 4], s1[rb + 5]); c67 = cvtpk(s1[rb + 6], s1[rb + 7]);
        }
        asm("v_permlane32_swap_b32 %0, %1" : "+v"(c01), "+v"(c45));
        asm("v_permlane32_swap_b32 %0, %1" : "+v"(c23), "+v"(c67));
        u32x4 pu = {c01, c23, c45, c67};
        pf[b2 * 2 + h8] = pu;
      }
    }

    __builtin_amdgcn_s_setprio(1);
#pragma unroll
    for (int kc = 0; kc < 4; kc++) {
      const bf16x8 pa = __builtin_bit_cast(bf16x8, pf[kc]);
      const bf16x8 v0 =
          *(const bf16x8*)&Vls[cur][l31][((kc * 2 + hi) ^ swz) << 3];
      const bf16x8 v1 =
          *(const bf16x8*)&Vls[cur][32 + l31][((kc * 2 + hi) ^ swz) << 3];
      o0 = __builtin_amdgcn_mfma_f32_32x32x16_bf16(pa, v0, o0, 0, 0, 0);
      o1 = __builtin_amdgcn_mfma_f32_32x32x16_bf16(pa, v1, o1, 0, 0, 0);
      asum = __builtin_amdgcn_mfma_f32_32x32x16_bf16(pa, onesB, asum, 0, 0, 0);
    }
    __builtin_amdgcn_s_setprio(0);
    cur ^= 1;
  }

  const int bb = bh >> 4, h = bh & 15;
#pragma unroll
  for (int r = 0; r < 16; r++) {
    const int rq = (r & 3) + 8 * (r >> 2) + 4 * hi;
    const float ir = 1.f / asum[r];
    const size_t base = ((size_t)(bb * SEQ + q0 + rq)) * DIMM + h * HD;
    vals[base + l31] = f2bf(o0[r] * ir);
    vals[base + 32 + l31] = f2bf(o1[r] * ir);
  }
}

// ---------------- GEMM2: out = vals @ WoutT^T + b (fp32 out, r8 version) ----------------
__global__ __launch_bounds__(256) void k_gemm_out(
    const short* __restrict__ A, const short* __restrict__ Bt,
    const float* __restrict__ bias, float* __restrict__ out) {
  __shared__ alignas(16) short Als[128][32];
  __shared__ alignas(16) short Bls[128][32];
  const int tid = threadIdx.x, lane = tid & 63, wid = tid >> 6;
  const int wr = wid >> 1, wc = wid & 1;
  const int bm = blockIdx.x, bn = blockIdx.y;
  const int fr = lane & 15, fg = lane >> 4;
  const int arow = lane >> 2, achk = lane & 3;
  f32x4 acc[4][4] = {};
  const short* Ap = A + (size_t)(bm * 128) * DIMM;
  const short* Bp = Bt + (size_t)(bn * 128) * DIMM;
  for (int k0 = 0; k0 < DIMM; k0 += 32) {
    __syncthreads();
#pragma unroll
    for (int c = 0; c < 2; c++) {
      const int r0 = (wid * 2 + c) * 16;
      gload16(Ap + (size_t)(r0 + arow) * DIMM + k0 + achk * 8, &Als[r0][0]);
      gload16(Bp + (size_t)(r0 + arow) * DIMM + k0 + achk * 8, &Bls[r0][0]);
    }
    __syncthreads();
    bf16x8 af[4], bfv[4];
#pragma unroll
    for (int i = 0; i < 4; i++) {
      af[i] = *(const bf16x8*)&Als[wr * 64 + i * 16 + fr][fg * 8];
      bfv[i] = *(const bf16x8*)&Bls[wc * 64 + i * 16 + fr][fg * 8];
    }
#pragma unroll
    for (int i = 0; i < 4; i++)
#pragma unroll
      for (int j = 0; j < 4; j++)
        acc[i][j] = __builtin_amdgcn_mfma_f32_16x16x32_bf16(af[i], bfv[j], acc[i][j], 0, 0, 0);
  }
#pragma unroll
  for (int i = 0; i < 4; i++) {
    const int row0 = bm * 128 + wr * 64 + i * 16 + fg * 4;
#pragma unroll
    for (int j = 0; j < 4; j++) {
      const int col = bn * 128 + wc * 64 + j * 16 + fr;
      const float bs = bias[col];
#pragma unroll
      for (int r = 0; r < 4; r++)
        out[(size_t)(row0 + r) * DIMM + col] = acc[i][j][r] + bs;
    }
  }
}

extern "C" void kernel_launch(void* const* d_in, const int* in_sizes, int n_in,
                              void* d_out, int out_size, void* d_ws, size_t ws_size,
                              hipStream_t stream) {
  (void)in_sizes; (void)n_in; (void)out_size;
  const float* x = (const float*)d_in[0];
  const float* Wqkv = (const float*)d_in[1];
  const float* bqkv = (const float*)d_in[2];
  const float* Wout = (const float*)d_in[3];
  const float* bout = (const float*)d_in[4];
  float* out = (float*)d_out;

  char* ws = (char*)d_ws;
  const size_t sz_wq = (size_t)3 * DIMM * DIMM * 2;
  const size_t sz_wo = (size_t)DIMM * DIMM * 2;
  const size_t sz_m = (size_t)MTOT * DIMM * 2;
  const size_t off_wq = 0;
  const size_t off_wo = off_wq + sz_wq;
  const size_t off_q = off_wo + sz_wo;
  const size_t off_k = off_q + sz_m;
  const size_t off_vt = off_k + sz_m;
  const size_t off_vals = off_vt + sz_m;  // doubles as xb
  const size_t need = off_vals + sz_m;
  if (ws_size < need) return;

  short* WqT = (short*)(ws + off_wq);
  short* WoT = (short*)(ws + off_wo);
  short* qws = (short*)(ws + off_q);
  short* kws = (short*)(ws + off_k);
  short* vtg = (short*)(ws + off_vt);
  short* xb = (short*)(ws + off_vals);
  short* valsws = (short*)(ws + off_vals);

  // idempotent host-side attribute (not a stream op; safe under graph capture)
  hipFuncSetAttribute((const void*)k_gemm_qkv,
                      hipFuncAttributeMaxDynamicSharedMemorySize, 98304);

  k_cvt<<<2048, 256, 0, stream>>>(x, xb, MTOT * DIMM / 8);
  k_transpose<<<dim3(3 * DIMM / 32, DIMM / 32), dim3(32, 8), 0, stream>>>(Wqkv, WqT, DIMM, 3 * DIMM);
  k_transpose<<<dim3(DIMM / 32, DIMM / 32), dim3(32, 8), 0, stream>>>(Wout, WoT, DIMM, DIMM);
  k_gemm_qkv<<<768, 512, 98304, stream>>>(xb, WqT, bqkv, qws, kws, vtg);
  k_attn<<<1024, 256, 0, stream>>>(qws, kws, vtg, valsws);
  k_gemm_out<<<dim3(MTOT / 128, DIMM / 128), 256, 0, stream>>>(valsws, WoT, bout, out);
}

// Round 12
// 213.003 us; speedup vs baseline: 1.0656x; 1.0656x over previous
//
#include <hip/hip_runtime.h>

// Fused MHA: qkv = x@Wqkv+b; attn per head; out = vals@Wout+b
// B=4, S=2048, D=1024, H=16, Hd=64. Internal compute bf16 MFMA + fp32 accum.
// Round 12: revert GEMM1 to r8 128^2 single-buffer (r9/r10/r11 pipeline
// experiments all regressed: at K=1024 + 16KB LDS, 8 blocks/CU inter-block
// overlap beats 1-block/CU deep pipelines). Merge the two W-transposes into
// one launch. attn/GEMM2 = r8 (best: 215.4 us).

typedef short bf16x8 __attribute__((ext_vector_type(8)));
typedef short bf16x4 __attribute__((ext_vector_type(4)));
typedef float f32x4 __attribute__((ext_vector_type(4)));
typedef float f32x16 __attribute__((ext_vector_type(16)));
typedef unsigned u32x4 __attribute__((ext_vector_type(4)));

#define DIMM 1024
#define NH 16
#define HD 64
#define SEQ 2048
#define NB 4
#define MTOT (NB * SEQ)  // 8192
#define SCQ 0.18033688f  // 0.125 * log2(e), folded into Q

__device__ __forceinline__ short f2bf(float f) {
  __bf16 h = (__bf16)f;
  return __builtin_bit_cast(short, h);
}

__device__ __forceinline__ unsigned cvtpk(float lo, float hi) {
  unsigned d;
  asm("v_cvt_pk_bf16_f32 %0, %1, %2" : "=v"(d) : "v"(lo), "v"(hi));
  return d;
}

__device__ __forceinline__ void gload16(const short* g, const short* l) {
  __builtin_amdgcn_global_load_lds(
      (const __attribute__((address_space(1))) unsigned int*)g,
      (__attribute__((address_space(3))) unsigned int*)l, 16, 0, 0);
}

// ---------------- x fp32 -> bf16 ----------------
__global__ __launch_bounds__(256) void k_cvt(const float* __restrict__ in,
                                             short* __restrict__ out, int n8) {
  const int stride = gridDim.x * blockDim.x;
  for (int i = blockIdx.x * blockDim.x + threadIdx.x; i < n8; i += stride) {
    const float4* p = (const float4*)(in + (size_t)i * 8);
    float4 a = p[0], b = p[1];
    bf16x8 h;
    h[0] = f2bf(a.x); h[1] = f2bf(a.y); h[2] = f2bf(a.z); h[3] = f2bf(a.w);
    h[4] = f2bf(b.x); h[5] = f2bf(b.y); h[6] = f2bf(b.z); h[7] = f2bf(b.w);
    *(bf16x8*)(out + (size_t)i * 8) = h;
  }
}

// ------- merged transpose + fp32->bf16 for both weights: out[n][k]=in[k][n] -------
// blockIdx.x < 96: Wqkv (N=3072); else Wout (N=1024), K=1024 for both.
__global__ void k_transpose2(const float* __restrict__ wqkv,
                             short* __restrict__ wqkvT,
                             const float* __restrict__ wout,
                             short* __restrict__ woutT) {
  __shared__ float tile[32][33];
  const int bx = blockIdx.x;
  const float* in;
  short* out;
  int N, n0;
  if (bx < 96) { in = wqkv; out = wqkvT; N = 3 * DIMM; n0 = bx * 32; }
  else         { in = wout; out = woutT; N = DIMM;     n0 = (bx - 96) * 32; }
  const int k0 = blockIdx.y * 32;
  const int tx = threadIdx.x, ty = threadIdx.y;
#pragma unroll
  for (int i = 0; i < 32; i += 8)
    tile[ty + i][tx] = in[(size_t)(k0 + ty + i) * N + n0 + tx];
  __syncthreads();
#pragma unroll
  for (int i = 0; i < 32; i += 8)
    out[(size_t)(n0 + ty + i) * DIMM + k0 + tx] = f2bf(tile[tx][ty + i]);
}

// ---------------- GEMM1: qkv = xb @ WqkvT^T + b; scatter Q(scaled)/K/V^T ----------------
__global__ __launch_bounds__(256) void k_gemm_qkv(
    const short* __restrict__ A, const short* __restrict__ Bt,
    const float* __restrict__ bias,
    short* __restrict__ qw, short* __restrict__ kw, short* __restrict__ vtg) {
  __shared__ alignas(16) short Als[128][32];
  __shared__ alignas(16) short Bls[128][32];
  const int tid = threadIdx.x, lane = tid & 63, wid = tid >> 6;
  const int wr = wid >> 1, wc = wid & 1;
  const int bm = blockIdx.x, bn = blockIdx.y;
  const int fr = lane & 15, fg = lane >> 4;
  const int arow = lane >> 2, achk = lane & 3;
  f32x4 acc[4][4] = {};
  const short* Ap = A + (size_t)(bm * 128) * DIMM;
  const short* Bp = Bt + (size_t)(bn * 128) * DIMM;
  for (int k0 = 0; k0 < DIMM; k0 += 32) {
    __syncthreads();
#pragma unroll
    for (int c = 0; c < 2; c++) {
      const int r0 = (wid * 2 + c) * 16;
      gload16(Ap + (size_t)(r0 + arow) * DIMM + k0 + achk * 8, &Als[r0][0]);
      gload16(Bp + (size_t)(r0 + arow) * DIMM + k0 + achk * 8, &Bls[r0][0]);
    }
    __syncthreads();
    bf16x8 af[4], bfv[4];
#pragma unroll
    for (int i = 0; i < 4; i++) {
      af[i] = *(const bf16x8*)&Als[wr * 64 + i * 16 + fr][fg * 8];
      bfv[i] = *(const bf16x8*)&Bls[wc * 64 + i * 16 + fr][fg * 8];
    }
#pragma unroll
    for (int i = 0; i < 4; i++)
#pragma unroll
      for (int j = 0; j < 4; j++)
        acc[i][j] = __builtin_amdgcn_mfma_f32_16x16x32_bf16(af[i], bfv[j], acc[i][j], 0, 0, 0);
  }
#pragma unroll
  for (int i = 0; i < 4; i++) {
    const int row0 = bm * 128 + wr * 64 + i * 16 + fg * 4;
    const int bb = row0 >> 11, s0 = row0 & 2047;
#pragma unroll
    for (int j = 0; j < 4; j++) {
      const int col = bn * 128 + wc * 64 + j * 16 + fr;
      const int h = col / 192;
      const int rem = col - h * 192;
      const int which = rem >> 6, d = rem & 63;
      const float bs = bias[col];
      if (which == 2) {
        bf16x4 pk;
#pragma unroll
        for (int r = 0; r < 4; r++) pk[r] = f2bf(acc[i][j][r] + bs);
        *(bf16x4*)&vtg[((size_t)((bb * NH + h) * HD + d)) * SEQ + s0] = pk;
      } else {
        short* dst = which == 0 ? qw : kw;
        const float scl = which == 0 ? SCQ : 1.f;
#pragma unroll
        for (int r = 0; r < 4; r++)
          dst[((size_t)((bb * NH + h) * SEQ + s0 + r)) * HD + d] =
              f2bf((acc[i][j][r] + bs) * scl);
      }
    }
  }
}

// ---------------- flash attention: 32x32x16 core, LDS-staged K/V (r8) ----------------
__global__ __launch_bounds__(256, 4) void k_attn(
    const short* __restrict__ qw, const short* __restrict__ kw,
    const short* __restrict__ vt, short* __restrict__ vals) {
  __shared__ alignas(16) short Kls[2][64][64];
  __shared__ alignas(16) short Vls[2][64][64];   // [d][key]
  const int tid = threadIdx.x, lane = tid & 63, w = tid >> 6;
  const int l31 = lane & 31, hi = lane >> 5;
  const int swz = (l31 & 7) ^ ((l31 & 8) >> 1);  // read-side row swizzle

  const int flat = blockIdx.x;
  const int wrk = (flat & 7) * 128 + (flat >> 3);
  const int qt = wrk & 15, bh = wrk >> 4;

  const short* Qp = qw + (size_t)bh * SEQ * HD;
  const short* Kp = kw + (size_t)bh * SEQ * HD;
  const short* Vtp = vt + (size_t)bh * HD * SEQ;

  const int q0 = qt * 128 + w * 32;

  bf16x8 qB[4];
#pragma unroll
  for (int dc = 0; dc < 4; dc++)
    qB[dc] = *(const bf16x8*)&Qp[(size_t)(q0 + l31) * HD + dc * 16 + hi * 8];

  bf16x8 onesB;
#pragma unroll
  for (int i = 0; i < 8; i++) onesB[i] = (short)0x3F80;

  f32x16 o0 = {}, o1 = {};
  f32x16 asum = {};

  const int sr8 = lane >> 3;
  const short* kstg = Kp + (size_t)(w * 16 + sr8) * HD;
  const short* vstg = Vtp + (size_t)(w * 16 + sr8) * SEQ;
  const int sslot0 = ((lane & 7) ^ sr8) * 8;
  const int sslot1 = ((lane & 7) ^ sr8 ^ 4) * 8;

  int cur = 0;
  gload16(kstg + sslot0, &Kls[0][w * 16][0]);
  gload16(vstg + sslot0, &Vls[0][w * 16][0]);
  gload16(kstg + (size_t)8 * HD + sslot1, &Kls[0][w * 16 + 8][0]);
  gload16(vstg + (size_t)8 * SEQ + sslot1, &Vls[0][w * 16 + 8][0]);

  for (int t = 0; t < SEQ / 64; t++) {
    __syncthreads();
    if (t + 1 < SEQ / 64) {
      const int kb = (t + 1) * 64;
      gload16(kstg + (size_t)kb * HD + sslot0, &Kls[cur ^ 1][w * 16][0]);
      gload16(vstg + kb + sslot0, &Vls[cur ^ 1][w * 16][0]);
      gload16(kstg + (size_t)(kb + 8) * HD + sslot1, &Kls[cur ^ 1][w * 16 + 8][0]);
      gload16(vstg + (size_t)8 * SEQ + kb + sslot1, &Vls[cur ^ 1][w * 16 + 8][0]);
    }

    f32x16 s0 = {}, s1 = {};
    __builtin_amdgcn_s_setprio(1);
#pragma unroll
    for (int dc = 0; dc < 4; dc++) {
      const bf16x8 k0 =
          *(const bf16x8*)&Kls[cur][l31][((dc * 2 + hi) ^ swz) << 3];
      const bf16x8 k1 =
          *(const bf16x8*)&Kls[cur][32 + l31][((dc * 2 + hi) ^ swz) << 3];
      s0 = __builtin_amdgcn_mfma_f32_32x32x16_bf16(k0, qB[dc], s0, 0, 0, 0);
      s1 = __builtin_amdgcn_mfma_f32_32x32x16_bf16(k1, qB[dc], s1, 0, 0, 0);
    }
    __builtin_amdgcn_s_setprio(0);

#pragma unroll
    for (int r = 0; r < 16; r++) s0[r] = exp2f(s0[r]);
#pragma unroll
    for (int r = 0; r < 16; r++) s1[r] = exp2f(s1[r]);

    u32x4 pf[4];
#pragma unroll
    for (int b2 = 0; b2 < 2; b2++) {
#pragma unroll
      for (int h8 = 0; h8 < 2; h8++) {
        const int rb = h8 * 8;
        unsigned c01, c23, c45, c67;
        if (b2 == 0) {
          c01 = cvtpk(s0[rb + 0], s0[rb + 1]); c23 = cvtpk(s0[rb + 2], s0[rb + 3]);
          c45 = cvtpk(s0[rb + 4], s0[rb + 5]); c67 = cvtpk(s0[rb + 6], s0[rb + 7]);
        } else {
          c01 = cvtpk(s1[rb + 0], s1[rb + 1]); c23 = cvtpk(s1[rb + 2], s1[rb + 3]);
          c45 = cvtpk(s1[rb + 4], s1[rb + 5]); c67 = cvtpk(s1[rb + 6], s1[rb + 7]);
        }
        asm("v_permlane32_swap_b32 %0, %1" : "+v"(c01), "+v"(c45));
        asm("v_permlane32_swap_b32 %0, %1" : "+v"(c23), "+v"(c67));
        u32x4 pu = {c01, c23, c45, c67};
        pf[b2 * 2 + h8] = pu;
      }
    }

    __builtin_amdgcn_s_setprio(1);
#pragma unroll
    for (int kc = 0; kc < 4; kc++) {
      const bf16x8 pa = __builtin_bit_cast(bf16x8, pf[kc]);
      const bf16x8 v0 =
          *(const bf16x8*)&Vls[cur][l31][((kc * 2 + hi) ^ swz) << 3];
      const bf16x8 v1 =
          *(const bf16x8*)&Vls[cur][32 + l31][((kc * 2 + hi) ^ swz) << 3];
      o0 = __builtin_amdgcn_mfma_f32_32x32x16_bf16(pa, v0, o0, 0, 0, 0);
      o1 = __builtin_amdgcn_mfma_f32_32x32x16_bf16(pa, v1, o1, 0, 0, 0);
      asum = __builtin_amdgcn_mfma_f32_32x32x16_bf16(pa, onesB, asum, 0, 0, 0);
    }
    __builtin_amdgcn_s_setprio(0);
    cur ^= 1;
  }

  const int bb = bh >> 4, h = bh & 15;
#pragma unroll
  for (int r = 0; r < 16; r++) {
    const int rq = (r & 3) + 8 * (r >> 2) + 4 * hi;
    const float ir = 1.f / asum[r];
    const size_t base = ((size_t)(bb * SEQ + q0 + rq)) * DIMM + h * HD;
    vals[base + l31] = f2bf(o0[r] * ir);
    vals[base + 32 + l31] = f2bf(o1[r] * ir);
  }
}

// ---------------- GEMM2: out = vals @ WoutT^T + b (fp32 out, r8 version) ----------------
__global__ __launch_bounds__(256) void k_gemm_out(
    const short* __restrict__ A, const short* __restrict__ Bt,
    const float* __restrict__ bias, float* __restrict__ out) {
  __shared__ alignas(16) short Als[128][32];
  __shared__ alignas(16) short Bls[128][32];
  const int tid = threadIdx.x, lane = tid & 63, wid = tid >> 6;
  const int wr = wid >> 1, wc = wid & 1;
  const int bm = blockIdx.x, bn = blockIdx.y;
  const int fr = lane & 15, fg = lane >> 4;
  const int arow = lane >> 2, achk = lane & 3;
  f32x4 acc[4][4] = {};
  const short* Ap = A + (size_t)(bm * 128) * DIMM;
  const short* Bp = Bt + (size_t)(bn * 128) * DIMM;
  for (int k0 = 0; k0 < DIMM; k0 += 32) {
    __syncthreads();
#pragma unroll
    for (int c = 0; c < 2; c++) {
      const int r0 = (wid * 2 + c) * 16;
      gload16(Ap + (size_t)(r0 + arow) * DIMM + k0 + achk * 8, &Als[r0][0]);
      gload16(Bp + (size_t)(r0 + arow) * DIMM + k0 + achk * 8, &Bls[r0][0]);
    }
    __syncthreads();
    bf16x8 af[4], bfv[4];
#pragma unroll
    for (int i = 0; i < 4; i++) {
      af[i] = *(const bf16x8*)&Als[wr * 64 + i * 16 + fr][fg * 8];
      bfv[i] = *(const bf16x8*)&Bls[wc * 64 + i * 16 + fr][fg * 8];
    }
#pragma unroll
    for (int i = 0; i < 4; i++)
#pragma unroll
      for (int j = 0; j < 4; j++)
        acc[i][j] = __builtin_amdgcn_mfma_f32_16x16x32_bf16(af[i], bfv[j], acc[i][j], 0, 0, 0);
  }
#pragma unroll
  for (int i = 0; i < 4; i++) {
    const int row0 = bm * 128 + wr * 64 + i * 16 + fg * 4;
#pragma unroll
    for (int j = 0; j < 4; j++) {
      const int col = bn * 128 + wc * 64 + j * 16 + fr;
      const float bs = bias[col];
#pragma unroll
      for (int r = 0; r < 4; r++)
        out[(size_t)(row0 + r) * DIMM + col] = acc[i][j][r] + bs;
    }
  }
}

extern "C" void kernel_launch(void* const* d_in, const int* in_sizes, int n_in,
                              void* d_out, int out_size, void* d_ws, size_t ws_size,
                              hipStream_t stream) {
  (void)in_sizes; (void)n_in; (void)out_size;
  const float* x = (const float*)d_in[0];
  const float* Wqkv = (const float*)d_in[1];
  const float* bqkv = (const float*)d_in[2];
  const float* Wout = (const float*)d_in[3];
  const float* bout = (const float*)d_in[4];
  float* out = (float*)d_out;

  char* ws = (char*)d_ws;
  const size_t sz_wq = (size_t)3 * DIMM * DIMM * 2;
  const size_t sz_wo = (size_t)DIMM * DIMM * 2;
  const size_t sz_m = (size_t)MTOT * DIMM * 2;
  const size_t off_wq = 0;
  const size_t off_wo = off_wq + sz_wq;
  const size_t off_q = off_wo + sz_wo;
  const size_t off_k = off_q + sz_m;
  const size_t off_vt = off_k + sz_m;
  const size_t off_vals = off_vt + sz_m;  // doubles as xb
  const size_t need = off_vals + sz_m;
  if (ws_size < need) return;

  short* WqT = (short*)(ws + off_wq);
  short* WoT = (short*)(ws + off_wo);
  short* qws = (short*)(ws + off_q);
  short* kws = (short*)(ws + off_k);
  short* vtg = (short*)(ws + off_vt);
  short* xb = (short*)(ws + off_vals);
  short* valsws = (short*)(ws + off_vals);

  k_cvt<<<2048, 256, 0, stream>>>(x, xb, MTOT * DIMM / 8);
  k_transpose2<<<dim3(128, 32), dim3(32, 8), 0, stream>>>(Wqkv, WqT, Wout, WoT);
  k_gemm_qkv<<<dim3(MTOT / 128, 3 * DIMM / 128), 256, 0, stream>>>(xb, WqT, bqkv, qws, kws, vtg);
  k_attn<<<1024, 256, 0, stream>>>(qws, kws, vtg, valsws);
  k_gemm_out<<<dim3(MTOT / 128, DIMM / 128), 256, 0, stream>>>(valsws, WoT, bout, out);
}

// Round 13
// 211.702 us; speedup vs baseline: 1.0722x; 1.0061x over previous
//
#include <hip/hip_runtime.h>

// Fused MHA: qkv = x@Wqkv+b; attn per head; out = vals@Wout+b
// B=4, S=2048, D=1024, H=16, Hd=64. Internal compute bf16 MFMA + fp32 accum.
// Round 13: merge k_cvt + k_transpose2 into one k_prep kernel (independent
// memory-bound work, now co-resident -> overlapped traffic + one fewer launch).
// GEMM1/GEMM2/attn unchanged from r12 (213.0 us).

typedef short bf16x8 __attribute__((ext_vector_type(8)));
typedef short bf16x4 __attribute__((ext_vector_type(4)));
typedef float f32x4 __attribute__((ext_vector_type(4)));
typedef float f32x16 __attribute__((ext_vector_type(16)));
typedef unsigned u32x4 __attribute__((ext_vector_type(4)));

#define DIMM 1024
#define NH 16
#define HD 64
#define SEQ 2048
#define NB 4
#define MTOT (NB * SEQ)  // 8192
#define SCQ 0.18033688f  // 0.125 * log2(e), folded into Q

__device__ __forceinline__ short f2bf(float f) {
  __bf16 h = (__bf16)f;
  return __builtin_bit_cast(short, h);
}

__device__ __forceinline__ unsigned cvtpk(float lo, float hi) {
  unsigned d;
  asm("v_cvt_pk_bf16_f32 %0, %1, %2" : "=v"(d) : "v"(lo), "v"(hi));
  return d;
}

__device__ __forceinline__ void gload16(const short* g, const short* l) {
  __builtin_amdgcn_global_load_lds(
      (const __attribute__((address_space(1))) unsigned int*)g,
      (__attribute__((address_space(3))) unsigned int*)l, 16, 0, 0);
}

// ---------------- prep: x fp32->bf16 (grid-stride) + both W transposes ----------------
// blocks [0,4096): transpose tiles (bx<96 -> Wqkv, else Wout), [4096,6144): cvt.
__global__ __launch_bounds__(256) void k_prep(
    const float* __restrict__ x, short* __restrict__ xb,
    const float* __restrict__ wqkv, short* __restrict__ wqkvT,
    const float* __restrict__ wout, short* __restrict__ woutT) {
  __shared__ float tile[32][33];
  const int b = blockIdx.x;
  if (b < 4096) {
    const int bx = b & 127, by = b >> 7;
    const float* in;
    short* out;
    int N, n0;
    if (bx < 96) { in = wqkv; out = wqkvT; N = 3 * DIMM; n0 = bx * 32; }
    else         { in = wout; out = woutT; N = DIMM;     n0 = (bx - 96) * 32; }
    const int k0 = by * 32;
    const int tx = threadIdx.x & 31, ty = threadIdx.x >> 5;
#pragma unroll
    for (int i = 0; i < 32; i += 8)
      tile[ty + i][tx] = in[(size_t)(k0 + ty + i) * N + n0 + tx];
    __syncthreads();
#pragma unroll
    for (int i = 0; i < 32; i += 8)
      out[(size_t)(n0 + ty + i) * DIMM + k0 + tx] = f2bf(tile[tx][ty + i]);
  } else {
    const int n8 = MTOT * DIMM / 8;
    const int stride = (gridDim.x - 4096) * 256;
    for (int i = (b - 4096) * 256 + threadIdx.x; i < n8; i += stride) {
      const float4* p = (const float4*)(x + (size_t)i * 8);
      float4 a = p[0], c = p[1];
      bf16x8 h;
      h[0] = f2bf(a.x); h[1] = f2bf(a.y); h[2] = f2bf(a.z); h[3] = f2bf(a.w);
      h[4] = f2bf(c.x); h[5] = f2bf(c.y); h[6] = f2bf(c.z); h[7] = f2bf(c.w);
      *(bf16x8*)(xb + (size_t)i * 8) = h;
    }
  }
}

// ---------------- GEMM1: qkv = xb @ WqkvT^T + b; scatter Q(scaled)/K/V^T ----------------
__global__ __launch_bounds__(256) void k_gemm_qkv(
    const short* __restrict__ A, const short* __restrict__ Bt,
    const float* __restrict__ bias,
    short* __restrict__ qw, short* __restrict__ kw, short* __restrict__ vtg) {
  __shared__ alignas(16) short Als[128][32];
  __shared__ alignas(16) short Bls[128][32];
  const int tid = threadIdx.x, lane = tid & 63, wid = tid >> 6;
  const int wr = wid >> 1, wc = wid & 1;
  const int bm = blockIdx.x, bn = blockIdx.y;
  const int fr = lane & 15, fg = lane >> 4;
  const int arow = lane >> 2, achk = lane & 3;
  f32x4 acc[4][4] = {};
  const short* Ap = A + (size_t)(bm * 128) * DIMM;
  const short* Bp = Bt + (size_t)(bn * 128) * DIMM;
  for (int k0 = 0; k0 < DIMM; k0 += 32) {
    __syncthreads();
#pragma unroll
    for (int c = 0; c < 2; c++) {
      const int r0 = (wid * 2 + c) * 16;
      gload16(Ap + (size_t)(r0 + arow) * DIMM + k0 + achk * 8, &Als[r0][0]);
      gload16(Bp + (size_t)(r0 + arow) * DIMM + k0 + achk * 8, &Bls[r0][0]);
    }
    __syncthreads();
    bf16x8 af[4], bfv[4];
#pragma unroll
    for (int i = 0; i < 4; i++) {
      af[i] = *(const bf16x8*)&Als[wr * 64 + i * 16 + fr][fg * 8];
      bfv[i] = *(const bf16x8*)&Bls[wc * 64 + i * 16 + fr][fg * 8];
    }
#pragma unroll
    for (int i = 0; i < 4; i++)
#pragma unroll
      for (int j = 0; j < 4; j++)
        acc[i][j] = __builtin_amdgcn_mfma_f32_16x16x32_bf16(af[i], bfv[j], acc[i][j], 0, 0, 0);
  }
#pragma unroll
  for (int i = 0; i < 4; i++) {
    const int row0 = bm * 128 + wr * 64 + i * 16 + fg * 4;
    const int bb = row0 >> 11, s0 = row0 & 2047;
#pragma unroll
    for (int j = 0; j < 4; j++) {
      const int col = bn * 128 + wc * 64 + j * 16 + fr;
      const int h = col / 192;
      const int rem = col - h * 192;
      const int which = rem >> 6, d = rem & 63;
      const float bs = bias[col];
      if (which == 2) {
        bf16x4 pk;
#pragma unroll
        for (int r = 0; r < 4; r++) pk[r] = f2bf(acc[i][j][r] + bs);
        *(bf16x4*)&vtg[((size_t)((bb * NH + h) * HD + d)) * SEQ + s0] = pk;
      } else {
        short* dst = which == 0 ? qw : kw;
        const float scl = which == 0 ? SCQ : 1.f;
#pragma unroll
        for (int r = 0; r < 4; r++)
          dst[((size_t)((bb * NH + h) * SEQ + s0 + r)) * HD + d] =
              f2bf((acc[i][j][r] + bs) * scl);
      }
    }
  }
}

// ---------------- flash attention: 32x32x16 core, LDS-staged K/V (r8) ----------------
__global__ __launch_bounds__(256, 4) void k_attn(
    const short* __restrict__ qw, const short* __restrict__ kw,
    const short* __restrict__ vt, short* __restrict__ vals) {
  __shared__ alignas(16) short Kls[2][64][64];
  __shared__ alignas(16) short Vls[2][64][64];   // [d][key]
  const int tid = threadIdx.x, lane = tid & 63, w = tid >> 6;
  const int l31 = lane & 31, hi = lane >> 5;
  const int swz = (l31 & 7) ^ ((l31 & 8) >> 1);  // read-side row swizzle

  const int flat = blockIdx.x;
  const int wrk = (flat & 7) * 128 + (flat >> 3);
  const int qt = wrk & 15, bh = wrk >> 4;

  const short* Qp = qw + (size_t)bh * SEQ * HD;
  const short* Kp = kw + (size_t)bh * SEQ * HD;
  const short* Vtp = vt + (size_t)bh * HD * SEQ;

  const int q0 = qt * 128 + w * 32;

  bf16x8 qB[4];
#pragma unroll
  for (int dc = 0; dc < 4; dc++)
    qB[dc] = *(const bf16x8*)&Qp[(size_t)(q0 + l31) * HD + dc * 16 + hi * 8];

  bf16x8 onesB;
#pragma unroll
  for (int i = 0; i < 8; i++) onesB[i] = (short)0x3F80;

  f32x16 o0 = {}, o1 = {};
  f32x16 asum = {};

  const int sr8 = lane >> 3;
  const short* kstg = Kp + (size_t)(w * 16 + sr8) * HD;
  const short* vstg = Vtp + (size_t)(w * 16 + sr8) * SEQ;
  const int sslot0 = ((lane & 7) ^ sr8) * 8;
  const int sslot1 = ((lane & 7) ^ sr8 ^ 4) * 8;

  int cur = 0;
  gload16(kstg + sslot0, &Kls[0][w * 16][0]);
  gload16(vstg + sslot0, &Vls[0][w * 16][0]);
  gload16(kstg + (size_t)8 * HD + sslot1, &Kls[0][w * 16 + 8][0]);
  gload16(vstg + (size_t)8 * SEQ + sslot1, &Vls[0][w * 16 + 8][0]);

  for (int t = 0; t < SEQ / 64; t++) {
    __syncthreads();
    if (t + 1 < SEQ / 64) {
      const int kb = (t + 1) * 64;
      gload16(kstg + (size_t)kb * HD + sslot0, &Kls[cur ^ 1][w * 16][0]);
      gload16(vstg + kb + sslot0, &Vls[cur ^ 1][w * 16][0]);
      gload16(kstg + (size_t)(kb + 8) * HD + sslot1, &Kls[cur ^ 1][w * 16 + 8][0]);
      gload16(vstg + (size_t)8 * SEQ + kb + sslot1, &Vls[cur ^ 1][w * 16 + 8][0]);
    }

    f32x16 s0 = {}, s1 = {};
    __builtin_amdgcn_s_setprio(1);
#pragma unroll
    for (int dc = 0; dc < 4; dc++) {
      const bf16x8 k0 =
          *(const bf16x8*)&Kls[cur][l31][((dc * 2 + hi) ^ swz) << 3];
      const bf16x8 k1 =
          *(const bf16x8*)&Kls[cur][32 + l31][((dc * 2 + hi) ^ swz) << 3];
      s0 = __builtin_amdgcn_mfma_f32_32x32x16_bf16(k0, qB[dc], s0, 0, 0, 0);
      s1 = __builtin_amdgcn_mfma_f32_32x32x16_bf16(k1, qB[dc], s1, 0, 0, 0);
    }
    __builtin_amdgcn_s_setprio(0);

#pragma unroll
    for (int r = 0; r < 16; r++) s0[r] = exp2f(s0[r]);
#pragma unroll
    for (int r = 0; r < 16; r++) s1[r] = exp2f(s1[r]);

    u32x4 pf[4];
#pragma unroll
    for (int b2 = 0; b2 < 2; b2++) {
#pragma unroll
      for (int h8 = 0; h8 < 2; h8++) {
        const int rb = h8 * 8;
        unsigned c01, c23, c45, c67;
        if (b2 == 0) {
          c01 = cvtpk(s0[rb + 0], s0[rb + 1]); c23 = cvtpk(s0[rb + 2], s0[rb + 3]);
          c45 = cvtpk(s0[rb + 4], s0[rb + 5]); c67 = cvtpk(s0[rb + 6], s0[rb + 7]);
        } else {
          c01 = cvtpk(s1[rb + 0], s1[rb + 1]); c23 = cvtpk(s1[rb + 2], s1[rb + 3]);
          c45 = cvtpk(s1[rb + 4], s1[rb + 5]); c67 = cvtpk(s1[rb + 6], s1[rb + 7]);
        }
        asm("v_permlane32_swap_b32 %0, %1" : "+v"(c01), "+v"(c45));
        asm("v_permlane32_swap_b32 %0, %1" : "+v"(c23), "+v"(c67));
        u32x4 pu = {c01, c23, c45, c67};
        pf[b2 * 2 + h8] = pu;
      }
    }

    __builtin_amdgcn_s_setprio(1);
#pragma unroll
    for (int kc = 0; kc < 4; kc++) {
      const bf16x8 pa = __builtin_bit_cast(bf16x8, pf[kc]);
      const bf16x8 v0 =
          *(const bf16x8*)&Vls[cur][l31][((kc * 2 + hi) ^ swz) << 3];
      const bf16x8 v1 =
          *(const bf16x8*)&Vls[cur][32 + l31][((kc * 2 + hi) ^ swz) << 3];
      o0 = __builtin_amdgcn_mfma_f32_32x32x16_bf16(pa, v0, o0, 0, 0, 0);
      o1 = __builtin_amdgcn_mfma_f32_32x32x16_bf16(pa, v1, o1, 0, 0, 0);
      asum = __builtin_amdgcn_mfma_f32_32x32x16_bf16(pa, onesB, asum, 0, 0, 0);
    }
    __builtin_amdgcn_s_setprio(0);
    cur ^= 1;
  }

  const int bb = bh >> 4, h = bh & 15;
#pragma unroll
  for (int r = 0; r < 16; r++) {
    const int rq = (r & 3) + 8 * (r >> 2) + 4 * hi;
    const float ir = 1.f / asum[r];
    const size_t base = ((size_t)(bb * SEQ + q0 + rq)) * DIMM + h * HD;
    vals[base + l31] = f2bf(o0[r] * ir);
    vals[base + 32 + l31] = f2bf(o1[r] * ir);
  }
}

// ---------------- GEMM2: out = vals @ WoutT^T + b (fp32 out, r8 version) ----------------
__global__ __launch_bounds__(256) void k_gemm_out(
    const short* __restrict__ A, const short* __restrict__ Bt,
    const float* __restrict__ bias, float* __restrict__ out) {
  __shared__ alignas(16) short Als[128][32];
  __shared__ alignas(16) short Bls[128][32];
  const int tid = threadIdx.x, lane = tid & 63, wid = tid >> 6;
  const int wr = wid >> 1, wc = wid & 1;
  const int bm = blockIdx.x, bn = blockIdx.y;
  const int fr = lane & 15, fg = lane >> 4;
  const int arow = lane >> 2, achk = lane & 3;
  f32x4 acc[4][4] = {};
  const short* Ap = A + (size_t)(bm * 128) * DIMM;
  const short* Bp = Bt + (size_t)(bn * 128) * DIMM;
  for (int k0 = 0; k0 < DIMM; k0 += 32) {
    __syncthreads();
#pragma unroll
    for (int c = 0; c < 2; c++) {
      const int r0 = (wid * 2 + c) * 16;
      gload16(Ap + (size_t)(r0 + arow) * DIMM + k0 + achk * 8, &Als[r0][0]);
      gload16(Bp + (size_t)(r0 + arow) * DIMM + k0 + achk * 8, &Bls[r0][0]);
    }
    __syncthreads();
    bf16x8 af[4], bfv[4];
#pragma unroll
    for (int i = 0; i < 4; i++) {
      af[i] = *(const bf16x8*)&Als[wr * 64 + i * 16 + fr][fg * 8];
      bfv[i] = *(const bf16x8*)&Bls[wc * 64 + i * 16 + fr][fg * 8];
    }
#pragma unroll
    for (int i = 0; i < 4; i++)
#pragma unroll
      for (int j = 0; j < 4; j++)
        acc[i][j] = __builtin_amdgcn_mfma_f32_16x16x32_bf16(af[i], bfv[j], acc[i][j], 0, 0, 0);
  }
#pragma unroll
  for (int i = 0; i < 4; i++) {
    const int row0 = bm * 128 + wr * 64 + i * 16 + fg * 4;
#pragma unroll
    for (int j = 0; j < 4; j++) {
      const int col = bn * 128 + wc * 64 + j * 16 + fr;
      const float bs = bias[col];
#pragma unroll
      for (int r = 0; r < 4; r++)
        out[(size_t)(row0 + r) * DIMM + col] = acc[i][j][r] + bs;
    }
  }
}

extern "C" void kernel_launch(void* const* d_in, const int* in_sizes, int n_in,
                              void* d_out, int out_size, void* d_ws, size_t ws_size,
                              hipStream_t stream) {
  (void)in_sizes; (void)n_in; (void)out_size;
  const float* x = (const float*)d_in[0];
  const float* Wqkv = (const float*)d_in[1];
  const float* bqkv = (const float*)d_in[2];
  const float* Wout = (const float*)d_in[3];
  const float* bout = (const float*)d_in[4];
  float* out = (float*)d_out;

  char* ws = (char*)d_ws;
  const size_t sz_wq = (size_t)3 * DIMM * DIMM * 2;
  const size_t sz_wo = (size_t)DIMM * DIMM * 2;
  const size_t sz_m = (size_t)MTOT * DIMM * 2;
  const size_t off_wq = 0;
  const size_t off_wo = off_wq + sz_wq;
  const size_t off_q = off_wo + sz_wo;
  const size_t off_k = off_q + sz_m;
  const size_t off_vt = off_k + sz_m;
  const size_t off_vals = off_vt + sz_m;  // doubles as xb
  const size_t need = off_vals + sz_m;
  if (ws_size < need) return;

  short* WqT = (short*)(ws + off_wq);
  short* WoT = (short*)(ws + off_wo);
  short* qws = (short*)(ws + off_q);
  short* kws = (short*)(ws + off_k);
  short* vtg = (short*)(ws + off_vt);
  short* xb = (short*)(ws + off_vals);
  short* valsws = (short*)(ws + off_vals);

  k_prep<<<6144, 256, 0, stream>>>(x, xb, Wqkv, WqT, Wout, WoT);
  k_gemm_qkv<<<dim3(MTOT / 128, 3 * DIMM / 128), 256, 0, stream>>>(xb, WqT, bqkv, qws, kws, vtg);
  k_attn<<<1024, 256, 0, stream>>>(qws, kws, vtg, valsws);
  k_gemm_out<<<dim3(MTOT / 128, DIMM / 128), 256, 0, stream>>>(valsws, WoT, bout, out);
}